// Round 23
// baseline (174.330 us; speedup 1.0000x reference)
//
#include <hip/hip_runtime.h>
#include <hip/hip_bf16.h>

#define V_N 30000
#define E_N 500000
#define XW  512                                // xform workers
#define GW  2048                               // gemv workers
#define SW  2048                               // scatter workers (covers E w/ guard)
#define K1B 4608                               // 512 periods of 9 (4 gemv,4 scat,1 xform)

typedef __attribute__((ext_vector_type(8))) short bf16x8;
typedef __attribute__((ext_vector_type(4))) float f32x4;

__device__ __forceinline__ float lrelu(float x) { return fmaxf(x, 0.2f * x); }
__device__ __forceinline__ unsigned short f2bf(float f) {
    __hip_bfloat16 h = __float2bfloat16(f);
    return *reinterpret_cast<unsigned short*>(&h);
}
__device__ __forceinline__ float bf_lo(unsigned u) { return __uint_as_float(u << 16); }
__device__ __forceinline__ float bf_hi(unsigned u) { return __uint_as_float(u & 0xffff0000u); }

// t + dpp(t); rows excluded by RMASK receive +0 (old=0, bound_ctrl).
template<int CTRL, int RMASK>
__device__ __forceinline__ float dpp_add(float t) {
    int b = __builtin_amdgcn_update_dpp(0, __float_as_int(t), CTRL, RMASK, 0xF, true);
    return t + __int_as_float(b);
}

// Sum over each independent 32-lane group, valid on all 32 lanes. (R13-proven)
__device__ __forceinline__ float group_sum(float t, int lane) {
    t = dpp_add<0x121, 0xF>(t);   // row_ror:1
    t = dpp_add<0x122, 0xF>(t);   // row_ror:2
    t = dpp_add<0x124, 0xF>(t);   // row_ror:4
    t = dpp_add<0x128, 0xF>(t);   // row_ror:8  -> each lane = its 16-row sum
    t = dpp_add<0x142, 0xA>(t);   // row_bcast15 -> rows 1,3 hold full 32-sum
    float u = __shfl_xor(t, 16);
    return (lane & 16) ? t : u;
}

// ---------------------------------------------------------------------------
// Histogram FIRST (standalone): unblocks scan immediately (R23 reorder).
// ---------------------------------------------------------------------------
__global__ __launch_bounds__(256) void hist_k(
    const int* __restrict__ dst, int* __restrict__ deg)
{
    int i = blockIdx.x * 256 + threadIdx.x;
    if (i < E_N) atomicAdd(&deg[dst[i]], 1);
}

// ---------------------------------------------------------------------------
// Exclusive scan of deg -> rowptr, cursor + in-block counting sort into perm[]
// (LDS cursors, descending degree). (R19-proven, verbatim)
// ---------------------------------------------------------------------------
__global__ __launch_bounds__(1024) void scan_k(
    const int* __restrict__ deg, int* __restrict__ rowptr, int* __restrict__ cursor,
    int* __restrict__ perm)
{
    __shared__ int wsum[16];
    __shared__ int carry_s;
    __shared__ int bh[128];
    __shared__ int bc[128];
    int tid = threadIdx.x;
    int lane = tid & 63, wv = tid >> 6;
    if (tid == 0) carry_s = 0;
    if (tid < 128) bh[tid] = 0;
    __syncthreads();
    for (int base = 0; base < V_N; base += 1024) {
        int i = base + tid;
        int v = (i < V_N) ? deg[i] : 0;
        int x = v;
        #pragma unroll
        for (int off = 1; off < 64; off <<= 1) {
            int t = __shfl_up(x, off, 64);
            if (lane >= off) x += t;
        }
        if (lane == 63) wsum[wv] = x;
        __syncthreads();
        if (wv == 0 && lane < 16) {
            int s = wsum[lane];
            #pragma unroll
            for (int off = 1; off < 16; off <<= 1) {
                int t = __shfl_up(s, off, 64);
                if (lane >= off) s += t;
            }
            wsum[lane] = s;
        }
        __syncthreads();
        int woff  = (wv == 0) ? 0 : wsum[wv - 1];
        int carry = carry_s;
        int excl  = carry + woff + x - v;
        if (i < V_N) {
            rowptr[i] = excl; cursor[i] = excl;
            atomicAdd(&bh[min(v, 127)], 1);
        }
        __syncthreads();
        if (tid == 1023) carry_s = carry + wsum[15];
        __syncthreads();
    }
    if (tid == 0) {
        rowptr[V_N] = carry_s;
        int off = 0;
        for (int b = 127; b >= 0; --b) { bc[b] = off; off += bh[b]; }
    }
    __syncthreads();
    for (int base = 0; base < V_N; base += 1024) {
        int i = base + tid;
        if (i < V_N) {
            int b = min(deg[i], 127);
            int p = atomicAdd(&bc[b], 1);
            perm[p] = i;
        }
    }
}

// ---------------------------------------------------------------------------
// K1' (triple-fused, INTERLEAVED — R22-proven mechanism): all three parts are
// dependency-free once scan has produced cursor.
// w%9: [0,4)=gemv, [4,8)=CSR scatter, 8=xform.
// ---------------------------------------------------------------------------
template<bool WN>
__global__ __launch_bounds__(256) void fused_k1(
    const float* __restrict__ nf, const float* __restrict__ ef,
    const int* __restrict__ src, const int* __restrict__ dst,
    int* __restrict__ cursor,
    const float* __restrict__ Was, const float* __restrict__ bas,
    const float* __restrict__ Wms, const float* __restrict__ bms,
    const float* __restrict__ Wad, const float* __restrict__ bad,
    const float* __restrict__ Wmd, const float* __restrict__ bmd,
    const float* __restrict__ Wae, const float* __restrict__ bae,
    const float* __restrict__ Wme, const float* __restrict__ bme,
    const float* __restrict__ Wwn, const float* __restrict__ bwn,
    uint4* __restrict__ tab_s, uint4* __restrict__ tab_d,
    uint2* __restrict__ wn_t,
    int2* __restrict__ csr2, unsigned* __restrict__ em)
{
    int tid  = threadIdx.x;
    int w    = blockIdx.x;
    int p    = w % 9, slot = w / 9;
    if (p < 4) {                               // ---- edge GEMV (2048 wkr) ----
        int gw = slot * 4 + p;
        int lane = tid & 63;
        int l15 = lane & 15, q = lane >> 4;
        bf16x8 B0, B1, B2, B3;
        #pragma unroll
        for (int i = 0; i < 8; ++i) {
            int k = q * 8 + i;
            B0[i] = (short)f2bf(Wae[k * 32 + l15]);
            B1[i] = (short)f2bf(Wae[k * 32 + 16 + l15]);
            B2[i] = (short)f2bf(Wme[k * 32 + l15]);
            B3[i] = (short)f2bf(Wme[k * 32 + 16 + l15]);
        }
        float ba0 = bae[l15], ba1 = bae[16 + l15];
        float bm0 = bme[l15], bm1 = bme[16 + l15];
        int wid = (gw * 256 + tid) >> 6;
        int nw  = (GW * 256) >> 6;             // 8192 waves
        const int ntiles = E_N / 16;           // 31250 exact
        for (int tile = wid; tile < ntiles; tile += nw) {
            int ebase = tile * 16;
            const float4* ap = (const float4*)(ef + (size_t)(ebase + l15) * 32 + q * 8);
            float4 a0 = ap[0], a1 = ap[1];
            bf16x8 A;
            A[0] = (short)f2bf(a0.x); A[1] = (short)f2bf(a0.y);
            A[2] = (short)f2bf(a0.z); A[3] = (short)f2bf(a0.w);
            A[4] = (short)f2bf(a1.x); A[5] = (short)f2bf(a1.y);
            A[6] = (short)f2bf(a1.z); A[7] = (short)f2bf(a1.w);
            f32x4 z = {0.f, 0.f, 0.f, 0.f};
            f32x4 D0 = __builtin_amdgcn_mfma_f32_16x16x32_bf16(A, B0, z, 0, 0, 0);
            f32x4 D1 = __builtin_amdgcn_mfma_f32_16x16x32_bf16(A, B1, z, 0, 0, 0);
            f32x4 D2 = __builtin_amdgcn_mfma_f32_16x16x32_bf16(A, B2, z, 0, 0, 0);
            f32x4 D3 = __builtin_amdgcn_mfma_f32_16x16x32_bf16(A, B3, z, 0, 0, 0);
            #pragma unroll
            for (int j = 0; j < 4; ++j) {
                int e = ebase + q * 4 + j;     // edge-order write, coalesced
                unsigned lo = f2bf(D0[j] + ba0) | ((unsigned)f2bf(D2[j] + bm0) << 16);
                unsigned hi = f2bf(D1[j] + ba1) | ((unsigned)f2bf(D3[j] + bm1) << 16);
                em[(size_t)e * 32 + l15]      = lo;
                em[(size_t)e * 32 + 16 + l15] = hi;
            }
        }
        return;
    }
    if (p < 8) {                               // ---- CSR scatter (2048 wkr) ----
        int sw = slot * 4 + (p - 4);
        int i = sw * 256 + tid;
        if (i < E_N) {
            int pp = atomicAdd(&cursor[dst[i]], 1);
            csr2[pp] = make_int2(src[i], i);
        }
        return;
    }
    // ---- node transform (512 wkr): 4 matrices + optional Wwn (R21-proven) ----
    int bid = slot;
    int lane = tid & 63;
    int l15 = lane & 15, q = lane >> 4;
    bf16x8 Bas0, Bas1, Bad0, Bad1, Bms0, Bms1, Bmd0, Bmd1, Bwn0, Bwn1;
    #pragma unroll
    for (int i = 0; i < 8; ++i) {
        int k = q * 8 + i;
        Bas0[i] = (short)f2bf(Was[k * 32 + l15]);
        Bas1[i] = (short)f2bf(Was[k * 32 + 16 + l15]);
        Bad0[i] = (short)f2bf(Wad[k * 32 + l15]);
        Bad1[i] = (short)f2bf(Wad[k * 32 + 16 + l15]);
        Bms0[i] = (short)f2bf(Wms[k * 32 + l15]);
        Bms1[i] = (short)f2bf(Wms[k * 32 + 16 + l15]);
        Bmd0[i] = (short)f2bf(Wmd[k * 32 + l15]);
        Bmd1[i] = (short)f2bf(Wmd[k * 32 + 16 + l15]);
        if (WN) {
            Bwn0[i] = (short)f2bf(Wwn[k * 32 + l15]);
            Bwn1[i] = (short)f2bf(Wwn[k * 32 + 16 + l15]);
        }
    }
    float bs0 = bas[l15], bs1 = bas[16 + l15];
    float bd0 = bad[l15], bd1 = bad[16 + l15];
    float bm0 = bms[l15], bm1 = bms[16 + l15];
    float bn0 = bmd[l15], bn1 = bmd[16 + l15];
    float bw0 = WN ? bwn[l15] : 0.f, bw1 = WN ? bwn[16 + l15] : 0.f;

    int wv = tid >> 6;                         // wave in block (0..3)
    const int ntiles = V_N / 4;                // 7500 (4 nodes per tile)
    for (int tile = bid * 4 + wv; tile < ntiles; tile += XW * 4) {
        int nbase = tile * 4;
        int rbase = nbase * 4;                 // 16 node-head rows
        const float4* ap = (const float4*)(nf + (size_t)(rbase + l15) * 32 + q * 8);
        float4 a0 = ap[0], a1 = ap[1];
        bf16x8 A;
        A[0] = (short)f2bf(a0.x); A[1] = (short)f2bf(a0.y);
        A[2] = (short)f2bf(a0.z); A[3] = (short)f2bf(a0.w);
        A[4] = (short)f2bf(a1.x); A[5] = (short)f2bf(a1.y);
        A[6] = (short)f2bf(a1.z); A[7] = (short)f2bf(a1.w);
        f32x4 z = {0.f, 0.f, 0.f, 0.f};
        f32x4 Das0 = __builtin_amdgcn_mfma_f32_16x16x32_bf16(A, Bas0, z, 0, 0, 0);
        f32x4 Das1 = __builtin_amdgcn_mfma_f32_16x16x32_bf16(A, Bas1, z, 0, 0, 0);
        f32x4 Dad0 = __builtin_amdgcn_mfma_f32_16x16x32_bf16(A, Bad0, z, 0, 0, 0);
        f32x4 Dad1 = __builtin_amdgcn_mfma_f32_16x16x32_bf16(A, Bad1, z, 0, 0, 0);
        f32x4 Dms0 = __builtin_amdgcn_mfma_f32_16x16x32_bf16(A, Bms0, z, 0, 0, 0);
        f32x4 Dms1 = __builtin_amdgcn_mfma_f32_16x16x32_bf16(A, Bms1, z, 0, 0, 0);
        f32x4 Dmd0 = __builtin_amdgcn_mfma_f32_16x16x32_bf16(A, Bmd0, z, 0, 0, 0);
        f32x4 Dmd1 = __builtin_amdgcn_mfma_f32_16x16x32_bf16(A, Bmd1, z, 0, 0, 0);
        int node = nbase + q;
        uint4 lo, hi;
        lo.x = f2bf(Das0[0] + bs0) | ((unsigned)f2bf(Das0[1] + bs0) << 16);
        lo.y = f2bf(Das0[2] + bs0) | ((unsigned)f2bf(Das0[3] + bs0) << 16);
        lo.z = f2bf(Dms0[0] + bm0) | ((unsigned)f2bf(Dms0[1] + bm0) << 16);
        lo.w = f2bf(Dms0[2] + bm0) | ((unsigned)f2bf(Dms0[3] + bm0) << 16);
        hi.x = f2bf(Das1[0] + bs1) | ((unsigned)f2bf(Das1[1] + bs1) << 16);
        hi.y = f2bf(Das1[2] + bs1) | ((unsigned)f2bf(Das1[3] + bs1) << 16);
        hi.z = f2bf(Dms1[0] + bm1) | ((unsigned)f2bf(Dms1[1] + bm1) << 16);
        hi.w = f2bf(Dms1[2] + bm1) | ((unsigned)f2bf(Dms1[3] + bm1) << 16);
        tab_s[(size_t)node * 32 + l15]      = lo;
        tab_s[(size_t)node * 32 + 16 + l15] = hi;
        uint4 lod, hid;
        lod.x = f2bf(Dad0[0] + bd0) | ((unsigned)f2bf(Dad0[1] + bd0) << 16);
        lod.y = f2bf(Dad0[2] + bd0) | ((unsigned)f2bf(Dad0[3] + bd0) << 16);
        lod.z = f2bf(Dmd0[0] + bn0) | ((unsigned)f2bf(Dmd0[1] + bn0) << 16);
        lod.w = f2bf(Dmd0[2] + bn0) | ((unsigned)f2bf(Dmd0[3] + bn0) << 16);
        hid.x = f2bf(Dad1[0] + bd1) | ((unsigned)f2bf(Dad1[1] + bd1) << 16);
        hid.y = f2bf(Dad1[2] + bd1) | ((unsigned)f2bf(Dad1[3] + bd1) << 16);
        hid.z = f2bf(Dmd1[0] + bn1) | ((unsigned)f2bf(Dmd1[1] + bn1) << 16);
        hid.w = f2bf(Dmd1[2] + bn1) | ((unsigned)f2bf(Dmd1[3] + bn1) << 16);
        tab_d[(size_t)node * 32 + l15]      = lod;
        tab_d[(size_t)node * 32 + 16 + l15] = hid;
        if (WN) {
            f32x4 Dwn0 = __builtin_amdgcn_mfma_f32_16x16x32_bf16(A, Bwn0, z, 0, 0, 0);
            f32x4 Dwn1 = __builtin_amdgcn_mfma_f32_16x16x32_bf16(A, Bwn1, z, 0, 0, 0);
            uint2 w0, w1;
            w0.x = f2bf(Dwn0[0] + bw0) | ((unsigned)f2bf(Dwn0[1] + bw0) << 16);
            w0.y = f2bf(Dwn0[2] + bw0) | ((unsigned)f2bf(Dwn0[3] + bw0) << 16);
            w1.x = f2bf(Dwn1[0] + bw1) | ((unsigned)f2bf(Dwn1[1] + bw1) << 16);
            w1.y = f2bf(Dwn1[2] + bw1) | ((unsigned)f2bf(Dwn1[3] + bw1) << 16);
            wn_t[(size_t)node * 32 + l15]      = w0;
            wn_t[(size_t)node * 32 + 16 + l15] = w1;
        }
    }
}

// ---------------------------------------------------------------------------
// Kernel C: per-dst aggregation, degree-sorted via perm[]. (R21/R22-proven)
// WN: epilogue = 1 uint2 bf16 table load; !WN: in-kernel Wwn GEMV fallback.
// ---------------------------------------------------------------------------
template<bool WN>
__global__ __launch_bounds__(256) void node_gather6(
    const int* __restrict__ rowptr, const int2* __restrict__ csr2,
    const unsigned* __restrict__ em, const uint4* __restrict__ tab_s,
    const uint4* __restrict__ tab_d, const uint2* __restrict__ wn_t,
    const float* __restrict__ Wdot,
    const float* __restrict__ Wwn, const float* __restrict__ bwn,
    const float* __restrict__ nf,
    const int* __restrict__ perm,
    float* __restrict__ out)
{
    __shared__ float ww[WN ? 1 : 1024];
    __shared__ float wd[32];
    int tid = threadIdx.x;
    if (!WN) for (int i = tid; i < 1024; i += 256) ww[i] = Wwn[i];
    if (tid < 32) wd[tid] = Wdot[tid] * 1.4426950408889634f;   // log2(e)
    __syncthreads();
    int lane = tid & 31;
    int n = perm[blockIdx.x * 8 + (tid >> 5)]; // degree-sorted assignment
    float wdl = wd[lane];

    float da[4], dm[4];
    {
        uint4 v = tab_d[(size_t)n * 32 + lane];
        da[0] = bf_lo(v.x); da[1] = bf_hi(v.x);
        da[2] = bf_lo(v.y); da[3] = bf_hi(v.y);
        dm[0] = bf_lo(v.z); dm[1] = bf_hi(v.z);
        dm[2] = bf_lo(v.w); dm[3] = bf_hi(v.w);
    }

    float acc0 = 0.f, acc1 = 0.f, acc2 = 0.f, acc3 = 0.f;
    float s0 = 0.f, s1 = 0.f, s2 = 0.f, s3 = 0.f;
    int p0 = rowptr[n], p1 = rowptr[n + 1];

    uint4 gc = make_uint4(0, 0, 0, 0);
    unsigned ec = 0;
    if (p0 < p1) {
        int2 c = csr2[p0];
        gc = tab_s[(size_t)c.x * 32 + lane];
        ec = em[(size_t)c.y * 32 + lane];
    }
    for (int p = p0; p < p1; ++p) {
        uint4 g = gc; unsigned ev = ec;
        if (p + 1 < p1) {                      // depth-1 prefetch
            int2 c = csr2[p + 1];
            gc = tab_s[(size_t)c.x * 32 + lane];
            ec = em[(size_t)c.y * 32 + lane];
        }
        float ea = bf_lo(ev), me = bf_hi(ev);
        float t0 = lrelu(bf_lo(g.x) + da[0] + ea) * wdl;
        float t1 = lrelu(bf_hi(g.x) + da[1] + ea) * wdl;
        float t2 = lrelu(bf_lo(g.y) + da[2] + ea) * wdl;
        float t3 = lrelu(bf_hi(g.y) + da[3] + ea) * wdl;
        t0 = group_sum(t0, lane);
        t1 = group_sum(t1, lane);
        t2 = group_sum(t2, lane);
        t3 = group_sum(t3, lane);
        float x0 = exp2f(t0), x1 = exp2f(t1);
        float x2 = exp2f(t2), x3 = exp2f(t3);
        float m0 = lrelu(bf_lo(g.z) + dm[0] + me);
        float m1 = lrelu(bf_hi(g.z) + dm[1] + me);
        float m2 = lrelu(bf_lo(g.w) + dm[2] + me);
        float m3 = lrelu(bf_hi(g.w) + dm[3] + me);
        acc0 = fmaf(x0, m0, acc0); s0 += x0;
        acc1 = fmaf(x1, m1, acc1); s1 += x1;
        acc2 = fmaf(x2, m2, acc2); s2 += x2;
        acc3 = fmaf(x3, m3, acc3); s3 += x3;
    }
    if (WN) {
        uint2 w = wn_t[(size_t)n * 32 + lane];
        float wn0 = bf_lo(w.x), wn1 = bf_hi(w.x);
        float wn2 = bf_lo(w.y), wn3 = bf_hi(w.y);
        float f0 = (s0 > 0.f) ? acc0 / s0 : 0.f;
        float f1 = (s1 > 0.f) ? acc1 / s1 : 0.f;
        float f2 = (s2 > 0.f) ? acc2 / s2 : 0.f;
        float f3 = (s3 > 0.f) ? acc3 / s3 : 0.f;
        size_t ob = (size_t)n * 128 + lane;
        out[ob]      = lrelu(f0 + wn0);
        out[ob + 32] = lrelu(f1 + wn1);
        out[ob + 64] = lrelu(f2 + wn2);
        out[ob + 96] = lrelu(f3 + wn3);
    } else {
        #pragma unroll
        for (int h = 0; h < 4; ++h) {
            float x = nf[(size_t)n * 128 + h * 32 + lane];
            float a = bwn[lane];
            #pragma unroll
            for (int k = 0; k < 32; ++k)
                a = fmaf(__shfl(x, k, 32), ww[k * 32 + lane], a);
            float accv = (h == 0) ? acc0 : (h == 1) ? acc1 : (h == 2) ? acc2 : acc3;
            float sv   = (h == 0) ? s0   : (h == 1) ? s1   : (h == 2) ? s2   : s3;
            float f = (sv > 0.f) ? accv / sv : 0.f;
            out[(size_t)n * 128 + h * 32 + lane] = lrelu(f + a);
        }
    }
}

extern "C" void kernel_launch(void* const* d_in, const int* in_sizes, int n_in,
                              void* d_out, int out_size, void* d_ws, size_t ws_size,
                              hipStream_t stream)
{
    const float* nf  = (const float*)d_in[0];
    const float* ef  = (const float*)d_in[1];
    const int*   src = (const int*)d_in[2];
    const int*   dst = (const int*)d_in[3];
    const float* Was = (const float*)d_in[4],  *bas = (const float*)d_in[5];
    const float* Wad = (const float*)d_in[6],  *bad = (const float*)d_in[7];
    const float* Wae = (const float*)d_in[8],  *bae = (const float*)d_in[9];
    const float* Wdot= (const float*)d_in[10];
    const float* Wms = (const float*)d_in[12], *bms = (const float*)d_in[13];
    const float* Wmd = (const float*)d_in[14], *bmd = (const float*)d_in[15];
    const float* Wme = (const float*)d_in[16], *bme = (const float*)d_in[17];
    const float* Wwn = (const float*)d_in[18], *bwn = (const float*)d_in[19];

    // ws layout: em (64) | tab_s (15.36) | tab_d (15.36) | [wn_t 7.68] | ints
    const size_t em_w  = (size_t)E_N * 32;             // u32 words
    const size_t tab_w = (size_t)V_N * 32;             // uint4 elems
    const size_t wn_w  = (size_t)V_N * 32;             // uint2 elems
    const size_t int_b = ((size_t)V_N * 3 + 1 + (size_t)E_N * 2) * 4;
    const size_t need_wn = em_w * 4 + tab_w * 16 * 2 + wn_w * 8 + int_b;
    const bool   wn_ok = (ws_size >= need_wn);

    unsigned* em     = (unsigned*)d_ws;
    uint4*    tab_s  = (uint4*)(em + em_w);
    uint4*    tab_d  = tab_s + tab_w;
    uint2*    wn_t   = (uint2*)(tab_d + tab_w);
    int*      ints   = wn_ok ? (int*)(wn_t + wn_w) : (int*)(tab_d + tab_w);
    int*      deg    = ints;                           // V
    int*      rowptr = deg + V_N;                      // V+1
    int*      cursor = rowptr + V_N + 1;               // V
    int2*     csr2   = (int2*)(cursor + V_N);          // E int2
    int*      perm   = (int*)(csr2 + E_N);             // V

    hipMemsetAsync(deg, 0, V_N * sizeof(int), stream);

    const int hbk = (E_N + 255) / 256;                 // 1954 blocks

    hist_k<<<hbk, 256, 0, stream>>>(dst, deg);
    scan_k<<<1, 1024, 0, stream>>>(deg, rowptr, cursor, perm);
    if (wn_ok) {
        fused_k1<true><<<K1B, 256, 0, stream>>>(
            nf, ef, src, dst, cursor, Was, bas, Wms, bms, Wad, bad, Wmd, bmd,
            Wae, bae, Wme, bme, Wwn, bwn, tab_s, tab_d, wn_t, csr2, em);
        node_gather6<true><<<3750, 256, 0, stream>>>(
            rowptr, csr2, em, tab_s, tab_d, wn_t, Wdot, Wwn, bwn, nf, perm,
            (float*)d_out);
    } else {
        fused_k1<false><<<K1B, 256, 0, stream>>>(
            nf, ef, src, dst, cursor, Was, bas, Wms, bms, Wad, bad, Wmd, bmd,
            Wae, bae, Wme, bme, Wwn, bwn, tab_s, tab_d, wn_t, csr2, em);
        node_gather6<false><<<3750, 256, 0, stream>>>(
            rowptr, csr2, em, tab_s, tab_d, wn_t, Wdot, Wwn, bwn, nf, perm,
            (float*)d_out);
    }
}

// Round 24
// 152.811 us; speedup vs baseline: 1.1408x; 1.1408x over previous
//
#include <hip/hip_runtime.h>
#include <hip/hip_bf16.h>

#define V_N 30000
#define E_N 500000
#define GWW 1536                               // gemv workers
#define SWW 1536                               // scatter workers (grid-stride)
#define XWW 1536                               // xform workers
#define K1B 4608                               // 512 periods of 9 (3:3:3)

typedef __attribute__((ext_vector_type(8))) short bf16x8;
typedef __attribute__((ext_vector_type(4))) float f32x4;

__device__ __forceinline__ float lrelu(float x) { return fmaxf(x, 0.2f * x); }
__device__ __forceinline__ unsigned short f2bf(float f) {
    __hip_bfloat16 h = __float2bfloat16(f);
    return *reinterpret_cast<unsigned short*>(&h);
}
__device__ __forceinline__ float bf_lo(unsigned u) { return __uint_as_float(u << 16); }
__device__ __forceinline__ float bf_hi(unsigned u) { return __uint_as_float(u & 0xffff0000u); }

// t + dpp(t); rows excluded by RMASK receive +0 (old=0, bound_ctrl).
template<int CTRL, int RMASK>
__device__ __forceinline__ float dpp_add(float t) {
    int b = __builtin_amdgcn_update_dpp(0, __float_as_int(t), CTRL, RMASK, 0xF, true);
    return t + __int_as_float(b);
}

// Sum over each independent 32-lane group, valid on all 32 lanes. (R13-proven)
__device__ __forceinline__ float group_sum(float t, int lane) {
    t = dpp_add<0x121, 0xF>(t);   // row_ror:1
    t = dpp_add<0x122, 0xF>(t);   // row_ror:2
    t = dpp_add<0x124, 0xF>(t);   // row_ror:4
    t = dpp_add<0x128, 0xF>(t);   // row_ror:8  -> each lane = its 16-row sum
    t = dpp_add<0x142, 0xA>(t);   // row_bcast15 -> rows 1,3 hold full 32-sum
    float u = __shfl_xor(t, 16);
    return (lane & 16) ? t : u;
}

// ---------------------------------------------------------------------------
// Histogram FIRST (standalone): unblocks scan immediately. (R23)
// ---------------------------------------------------------------------------
__global__ __launch_bounds__(256) void hist_k(
    const int* __restrict__ dst, int* __restrict__ deg)
{
    int i = blockIdx.x * 256 + threadIdx.x;
    if (i < E_N) atomicAdd(&deg[dst[i]], 1);
}

// ---------------------------------------------------------------------------
// Exclusive scan + counting sort, int4-vectorized (4 elems/thread):
// 8 chunk-iterations instead of 30 -> barrier latency cut ~3.75x.
// V_N = 7500*4 exactly; deg is 16B-aligned in the ws layout.
// ---------------------------------------------------------------------------
__global__ __launch_bounds__(1024) void scan_k(
    const int* __restrict__ deg, int* __restrict__ rowptr, int* __restrict__ cursor,
    int* __restrict__ perm)
{
    __shared__ int wsum[16];
    __shared__ int carry_s;
    __shared__ int bh[128];
    __shared__ int bc[128];
    int tid = threadIdx.x;
    int lane = tid & 63, wv = tid >> 6;
    if (tid == 0) carry_s = 0;
    if (tid < 128) bh[tid] = 0;
    __syncthreads();
    const int NG = V_N / 4;                    // 7500 int4 groups (exact)
    for (int base = 0; base < NG; base += 1024) {
        int gi = base + tid;
        int4 v = make_int4(0, 0, 0, 0);
        if (gi < NG) v = ((const int4*)deg)[gi];
        int s = v.x + v.y + v.z + v.w;
        int x = s;
        #pragma unroll
        for (int off = 1; off < 64; off <<= 1) {
            int t = __shfl_up(x, off, 64);
            if (lane >= off) x += t;
        }
        if (lane == 63) wsum[wv] = x;
        __syncthreads();
        if (wv == 0 && lane < 16) {
            int s2 = wsum[lane];
            #pragma unroll
            for (int off = 1; off < 16; off <<= 1) {
                int t = __shfl_up(s2, off, 64);
                if (lane >= off) s2 += t;
            }
            wsum[lane] = s2;
        }
        __syncthreads();
        int woff  = (wv == 0) ? 0 : wsum[wv - 1];
        int carry = carry_s;
        int excl  = carry + woff + x - s;
        if (gi < NG) {
            int i = gi * 4;
            int e0 = excl, e1 = e0 + v.x, e2 = e1 + v.y, e3 = e2 + v.z;
            rowptr[i] = e0; rowptr[i+1] = e1; rowptr[i+2] = e2; rowptr[i+3] = e3;
            cursor[i] = e0; cursor[i+1] = e1; cursor[i+2] = e2; cursor[i+3] = e3;
            atomicAdd(&bh[min(v.x, 127)], 1);
            atomicAdd(&bh[min(v.y, 127)], 1);
            atomicAdd(&bh[min(v.z, 127)], 1);
            atomicAdd(&bh[min(v.w, 127)], 1);
        }
        __syncthreads();
        if (tid == 1023) carry_s = carry + wsum[15];
        __syncthreads();
    }
    if (tid == 0) {
        rowptr[V_N] = carry_s;
        int off = 0;                           // descending: big bins first
        for (int b = 127; b >= 0; --b) { bc[b] = off; off += bh[b]; }
    }
    __syncthreads();
    for (int base = 0; base < NG; base += 1024) {
        int gi = base + tid;
        if (gi < NG) {
            int4 v = ((const int4*)deg)[gi];
            int i = gi * 4;
            int p0 = atomicAdd(&bc[min(v.x, 127)], 1); perm[p0] = i;
            int p1 = atomicAdd(&bc[min(v.y, 127)], 1); perm[p1] = i + 1;
            int p2 = atomicAdd(&bc[min(v.z, 127)], 1); perm[p2] = i + 2;
            int p3 = atomicAdd(&bc[min(v.w, 127)], 1); perm[p3] = i + 3;
        }
    }
}

// ---------------------------------------------------------------------------
// K1 (triple-fused, interleaved 3:3:3 — R24 rebalance: xform share 1/9 -> 3/9
// to kill the solo-tail that dominated R22/R23's K1 duration).
// w%9: [0,3)=gemv, [3,6)=CSR scatter (grid-stride), [6,9)=xform.
// ---------------------------------------------------------------------------
template<bool WN>
__global__ __launch_bounds__(256) void fused_k1(
    const float* __restrict__ nf, const float* __restrict__ ef,
    const int* __restrict__ src, const int* __restrict__ dst,
    int* __restrict__ cursor,
    const float* __restrict__ Was, const float* __restrict__ bas,
    const float* __restrict__ Wms, const float* __restrict__ bms,
    const float* __restrict__ Wad, const float* __restrict__ bad,
    const float* __restrict__ Wmd, const float* __restrict__ bmd,
    const float* __restrict__ Wae, const float* __restrict__ bae,
    const float* __restrict__ Wme, const float* __restrict__ bme,
    const float* __restrict__ Wwn, const float* __restrict__ bwn,
    uint4* __restrict__ tab_s, uint4* __restrict__ tab_d,
    uint2* __restrict__ wn_t,
    int2* __restrict__ csr2, unsigned* __restrict__ em)
{
    int tid  = threadIdx.x;
    int w    = blockIdx.x;
    int p    = w % 9, slot = w / 9;
    if (p < 3) {                               // ---- edge GEMV (1536 wkr) ----
        int gw = slot * 3 + p;
        int lane = tid & 63;
        int l15 = lane & 15, q = lane >> 4;
        bf16x8 B0, B1, B2, B3;
        #pragma unroll
        for (int i = 0; i < 8; ++i) {
            int k = q * 8 + i;
            B0[i] = (short)f2bf(Wae[k * 32 + l15]);
            B1[i] = (short)f2bf(Wae[k * 32 + 16 + l15]);
            B2[i] = (short)f2bf(Wme[k * 32 + l15]);
            B3[i] = (short)f2bf(Wme[k * 32 + 16 + l15]);
        }
        float ba0 = bae[l15], ba1 = bae[16 + l15];
        float bm0 = bme[l15], bm1 = bme[16 + l15];
        int wid = (gw * 256 + tid) >> 6;
        int nw  = (GWW * 256) >> 6;            // 6144 waves
        const int ntiles = E_N / 16;           // 31250 exact
        for (int tile = wid; tile < ntiles; tile += nw) {
            int ebase = tile * 16;
            const float4* ap = (const float4*)(ef + (size_t)(ebase + l15) * 32 + q * 8);
            float4 a0 = ap[0], a1 = ap[1];
            bf16x8 A;
            A[0] = (short)f2bf(a0.x); A[1] = (short)f2bf(a0.y);
            A[2] = (short)f2bf(a0.z); A[3] = (short)f2bf(a0.w);
            A[4] = (short)f2bf(a1.x); A[5] = (short)f2bf(a1.y);
            A[6] = (short)f2bf(a1.z); A[7] = (short)f2bf(a1.w);
            f32x4 z = {0.f, 0.f, 0.f, 0.f};
            f32x4 D0 = __builtin_amdgcn_mfma_f32_16x16x32_bf16(A, B0, z, 0, 0, 0);
            f32x4 D1 = __builtin_amdgcn_mfma_f32_16x16x32_bf16(A, B1, z, 0, 0, 0);
            f32x4 D2 = __builtin_amdgcn_mfma_f32_16x16x32_bf16(A, B2, z, 0, 0, 0);
            f32x4 D3 = __builtin_amdgcn_mfma_f32_16x16x32_bf16(A, B3, z, 0, 0, 0);
            #pragma unroll
            for (int j = 0; j < 4; ++j) {
                int e = ebase + q * 4 + j;     // edge-order write, coalesced
                unsigned lo = f2bf(D0[j] + ba0) | ((unsigned)f2bf(D2[j] + bm0) << 16);
                unsigned hi = f2bf(D1[j] + ba1) | ((unsigned)f2bf(D3[j] + bm1) << 16);
                em[(size_t)e * 32 + l15]      = lo;
                em[(size_t)e * 32 + 16 + l15] = hi;
            }
        }
        return;
    }
    if (p < 6) {                               // ---- CSR scatter (1536 wkr) ----
        int sw = slot * 3 + (p - 3);
        for (int i = sw * 256 + tid; i < E_N; i += SWW * 256) {
            int pp = atomicAdd(&cursor[dst[i]], 1);
            csr2[pp] = make_int2(src[i], i);
        }
        return;
    }
    // ---- node transform (1536 wkr): 4 matrices + optional Wwn (R21-proven) ----
    int bid = slot * 3 + (p - 6);
    int lane = tid & 63;
    int l15 = lane & 15, q = lane >> 4;
    bf16x8 Bas0, Bas1, Bad0, Bad1, Bms0, Bms1, Bmd0, Bmd1, Bwn0, Bwn1;
    #pragma unroll
    for (int i = 0; i < 8; ++i) {
        int k = q * 8 + i;
        Bas0[i] = (short)f2bf(Was[k * 32 + l15]);
        Bas1[i] = (short)f2bf(Was[k * 32 + 16 + l15]);
        Bad0[i] = (short)f2bf(Wad[k * 32 + l15]);
        Bad1[i] = (short)f2bf(Wad[k * 32 + 16 + l15]);
        Bms0[i] = (short)f2bf(Wms[k * 32 + l15]);
        Bms1[i] = (short)f2bf(Wms[k * 32 + 16 + l15]);
        Bmd0[i] = (short)f2bf(Wmd[k * 32 + l15]);
        Bmd1[i] = (short)f2bf(Wmd[k * 32 + 16 + l15]);
        if (WN) {
            Bwn0[i] = (short)f2bf(Wwn[k * 32 + l15]);
            Bwn1[i] = (short)f2bf(Wwn[k * 32 + 16 + l15]);
        }
    }
    float bs0 = bas[l15], bs1 = bas[16 + l15];
    float bd0 = bad[l15], bd1 = bad[16 + l15];
    float bm0 = bms[l15], bm1 = bms[16 + l15];
    float bn0 = bmd[l15], bn1 = bmd[16 + l15];
    float bw0 = WN ? bwn[l15] : 0.f, bw1 = WN ? bwn[16 + l15] : 0.f;

    int wv = tid >> 6;                         // wave in block (0..3)
    const int ntiles = V_N / 4;                // 7500 (4 nodes per tile)
    for (int tile = bid * 4 + wv; tile < ntiles; tile += XWW * 4) {
        int nbase = tile * 4;
        int rbase = nbase * 4;                 // 16 node-head rows
        const float4* ap = (const float4*)(nf + (size_t)(rbase + l15) * 32 + q * 8);
        float4 a0 = ap[0], a1 = ap[1];
        bf16x8 A;
        A[0] = (short)f2bf(a0.x); A[1] = (short)f2bf(a0.y);
        A[2] = (short)f2bf(a0.z); A[3] = (short)f2bf(a0.w);
        A[4] = (short)f2bf(a1.x); A[5] = (short)f2bf(a1.y);
        A[6] = (short)f2bf(a1.z); A[7] = (short)f2bf(a1.w);
        f32x4 z = {0.f, 0.f, 0.f, 0.f};
        f32x4 Das0 = __builtin_amdgcn_mfma_f32_16x16x32_bf16(A, Bas0, z, 0, 0, 0);
        f32x4 Das1 = __builtin_amdgcn_mfma_f32_16x16x32_bf16(A, Bas1, z, 0, 0, 0);
        f32x4 Dad0 = __builtin_amdgcn_mfma_f32_16x16x32_bf16(A, Bad0, z, 0, 0, 0);
        f32x4 Dad1 = __builtin_amdgcn_mfma_f32_16x16x32_bf16(A, Bad1, z, 0, 0, 0);
        f32x4 Dms0 = __builtin_amdgcn_mfma_f32_16x16x32_bf16(A, Bms0, z, 0, 0, 0);
        f32x4 Dms1 = __builtin_amdgcn_mfma_f32_16x16x32_bf16(A, Bms1, z, 0, 0, 0);
        f32x4 Dmd0 = __builtin_amdgcn_mfma_f32_16x16x32_bf16(A, Bmd0, z, 0, 0, 0);
        f32x4 Dmd1 = __builtin_amdgcn_mfma_f32_16x16x32_bf16(A, Bmd1, z, 0, 0, 0);
        int node = nbase + q;
        uint4 lo, hi;
        lo.x = f2bf(Das0[0] + bs0) | ((unsigned)f2bf(Das0[1] + bs0) << 16);
        lo.y = f2bf(Das0[2] + bs0) | ((unsigned)f2bf(Das0[3] + bs0) << 16);
        lo.z = f2bf(Dms0[0] + bm0) | ((unsigned)f2bf(Dms0[1] + bm0) << 16);
        lo.w = f2bf(Dms0[2] + bm0) | ((unsigned)f2bf(Dms0[3] + bm0) << 16);
        hi.x = f2bf(Das1[0] + bs1) | ((unsigned)f2bf(Das1[1] + bs1) << 16);
        hi.y = f2bf(Das1[2] + bs1) | ((unsigned)f2bf(Das1[3] + bs1) << 16);
        hi.z = f2bf(Dms1[0] + bm1) | ((unsigned)f2bf(Dms1[1] + bm1) << 16);
        hi.w = f2bf(Dms1[2] + bm1) | ((unsigned)f2bf(Dms1[3] + bm1) << 16);
        tab_s[(size_t)node * 32 + l15]      = lo;
        tab_s[(size_t)node * 32 + 16 + l15] = hi;
        uint4 lod, hid;
        lod.x = f2bf(Dad0[0] + bd0) | ((unsigned)f2bf(Dad0[1] + bd0) << 16);
        lod.y = f2bf(Dad0[2] + bd0) | ((unsigned)f2bf(Dad0[3] + bd0) << 16);
        lod.z = f2bf(Dmd0[0] + bn0) | ((unsigned)f2bf(Dmd0[1] + bn0) << 16);
        lod.w = f2bf(Dmd0[2] + bn0) | ((unsigned)f2bf(Dmd0[3] + bn0) << 16);
        hid.x = f2bf(Dad1[0] + bd1) | ((unsigned)f2bf(Dad1[1] + bd1) << 16);
        hid.y = f2bf(Dad1[2] + bd1) | ((unsigned)f2bf(Dad1[3] + bd1) << 16);
        hid.z = f2bf(Dmd1[0] + bn1) | ((unsigned)f2bf(Dmd1[1] + bn1) << 16);
        hid.w = f2bf(Dmd1[2] + bn1) | ((unsigned)f2bf(Dmd1[3] + bn1) << 16);
        tab_d[(size_t)node * 32 + l15]      = lod;
        tab_d[(size_t)node * 32 + 16 + l15] = hid;
        if (WN) {
            f32x4 Dwn0 = __builtin_amdgcn_mfma_f32_16x16x32_bf16(A, Bwn0, z, 0, 0, 0);
            f32x4 Dwn1 = __builtin_amdgcn_mfma_f32_16x16x32_bf16(A, Bwn1, z, 0, 0, 0);
            uint2 w0, w1;
            w0.x = f2bf(Dwn0[0] + bw0) | ((unsigned)f2bf(Dwn0[1] + bw0) << 16);
            w0.y = f2bf(Dwn0[2] + bw0) | ((unsigned)f2bf(Dwn0[3] + bw0) << 16);
            w1.x = f2bf(Dwn1[0] + bw1) | ((unsigned)f2bf(Dwn1[1] + bw1) << 16);
            w1.y = f2bf(Dwn1[2] + bw1) | ((unsigned)f2bf(Dwn1[3] + bw1) << 16);
            wn_t[(size_t)node * 32 + l15]      = w0;
            wn_t[(size_t)node * 32 + 16 + l15] = w1;
        }
    }
}

// ---------------------------------------------------------------------------
// Kernel C: per-dst aggregation, degree-sorted via perm[]. (R21/R22-proven)
// WN: epilogue = 1 uint2 bf16 table load; !WN: in-kernel Wwn GEMV fallback.
// ---------------------------------------------------------------------------
template<bool WN>
__global__ __launch_bounds__(256) void node_gather6(
    const int* __restrict__ rowptr, const int2* __restrict__ csr2,
    const unsigned* __restrict__ em, const uint4* __restrict__ tab_s,
    const uint4* __restrict__ tab_d, const uint2* __restrict__ wn_t,
    const float* __restrict__ Wdot,
    const float* __restrict__ Wwn, const float* __restrict__ bwn,
    const float* __restrict__ nf,
    const int* __restrict__ perm,
    float* __restrict__ out)
{
    __shared__ float ww[WN ? 1 : 1024];
    __shared__ float wd[32];
    int tid = threadIdx.x;
    if (!WN) for (int i = tid; i < 1024; i += 256) ww[i] = Wwn[i];
    if (tid < 32) wd[tid] = Wdot[tid] * 1.4426950408889634f;   // log2(e)
    __syncthreads();
    int lane = tid & 31;
    int n = perm[blockIdx.x * 8 + (tid >> 5)]; // degree-sorted assignment
    float wdl = wd[lane];

    float da[4], dm[4];
    {
        uint4 v = tab_d[(size_t)n * 32 + lane];
        da[0] = bf_lo(v.x); da[1] = bf_hi(v.x);
        da[2] = bf_lo(v.y); da[3] = bf_hi(v.y);
        dm[0] = bf_lo(v.z); dm[1] = bf_hi(v.z);
        dm[2] = bf_lo(v.w); dm[3] = bf_hi(v.w);
    }

    float acc0 = 0.f, acc1 = 0.f, acc2 = 0.f, acc3 = 0.f;
    float s0 = 0.f, s1 = 0.f, s2 = 0.f, s3 = 0.f;
    int p0 = rowptr[n], p1 = rowptr[n + 1];

    uint4 gc = make_uint4(0, 0, 0, 0);
    unsigned ec = 0;
    if (p0 < p1) {
        int2 c = csr2[p0];
        gc = tab_s[(size_t)c.x * 32 + lane];
        ec = em[(size_t)c.y * 32 + lane];
    }
    for (int p = p0; p < p1; ++p) {
        uint4 g = gc; unsigned ev = ec;
        if (p + 1 < p1) {                      // depth-1 prefetch
            int2 c = csr2[p + 1];
            gc = tab_s[(size_t)c.x * 32 + lane];
            ec = em[(size_t)c.y * 32 + lane];
        }
        float ea = bf_lo(ev), me = bf_hi(ev);
        float t0 = lrelu(bf_lo(g.x) + da[0] + ea) * wdl;
        float t1 = lrelu(bf_hi(g.x) + da[1] + ea) * wdl;
        float t2 = lrelu(bf_lo(g.y) + da[2] + ea) * wdl;
        float t3 = lrelu(bf_hi(g.y) + da[3] + ea) * wdl;
        t0 = group_sum(t0, lane);
        t1 = group_sum(t1, lane);
        t2 = group_sum(t2, lane);
        t3 = group_sum(t3, lane);
        float x0 = exp2f(t0), x1 = exp2f(t1);
        float x2 = exp2f(t2), x3 = exp2f(t3);
        float m0 = lrelu(bf_lo(g.z) + dm[0] + me);
        float m1 = lrelu(bf_hi(g.z) + dm[1] + me);
        float m2 = lrelu(bf_lo(g.w) + dm[2] + me);
        float m3 = lrelu(bf_hi(g.w) + dm[3] + me);
        acc0 = fmaf(x0, m0, acc0); s0 += x0;
        acc1 = fmaf(x1, m1, acc1); s1 += x1;
        acc2 = fmaf(x2, m2, acc2); s2 += x2;
        acc3 = fmaf(x3, m3, acc3); s3 += x3;
    }
    if (WN) {
        uint2 w = wn_t[(size_t)n * 32 + lane];
        float wn0 = bf_lo(w.x), wn1 = bf_hi(w.x);
        float wn2 = bf_lo(w.y), wn3 = bf_hi(w.y);
        float f0 = (s0 > 0.f) ? acc0 / s0 : 0.f;
        float f1 = (s1 > 0.f) ? acc1 / s1 : 0.f;
        float f2 = (s2 > 0.f) ? acc2 / s2 : 0.f;
        float f3 = (s3 > 0.f) ? acc3 / s3 : 0.f;
        size_t ob = (size_t)n * 128 + lane;
        out[ob]      = lrelu(f0 + wn0);
        out[ob + 32] = lrelu(f1 + wn1);
        out[ob + 64] = lrelu(f2 + wn2);
        out[ob + 96] = lrelu(f3 + wn3);
    } else {
        #pragma unroll
        for (int h = 0; h < 4; ++h) {
            float x = nf[(size_t)n * 128 + h * 32 + lane];
            float a = bwn[lane];
            #pragma unroll
            for (int k = 0; k < 32; ++k)
                a = fmaf(__shfl(x, k, 32), ww[k * 32 + lane], a);
            float accv = (h == 0) ? acc0 : (h == 1) ? acc1 : (h == 2) ? acc2 : acc3;
            float sv   = (h == 0) ? s0   : (h == 1) ? s1   : (h == 2) ? s2   : s3;
            float f = (sv > 0.f) ? accv / sv : 0.f;
            out[(size_t)n * 128 + h * 32 + lane] = lrelu(f + a);
        }
    }
}

extern "C" void kernel_launch(void* const* d_in, const int* in_sizes, int n_in,
                              void* d_out, int out_size, void* d_ws, size_t ws_size,
                              hipStream_t stream)
{
    const float* nf  = (const float*)d_in[0];
    const float* ef  = (const float*)d_in[1];
    const int*   src = (const int*)d_in[2];
    const int*   dst = (const int*)d_in[3];
    const float* Was = (const float*)d_in[4],  *bas = (const float*)d_in[5];
    const float* Wad = (const float*)d_in[6],  *bad = (const float*)d_in[7];
    const float* Wae = (const float*)d_in[8],  *bae = (const float*)d_in[9];
    const float* Wdot= (const float*)d_in[10];
    const float* Wms = (const float*)d_in[12], *bms = (const float*)d_in[13];
    const float* Wmd = (const float*)d_in[14], *bmd = (const float*)d_in[15];
    const float* Wme = (const float*)d_in[16], *bme = (const float*)d_in[17];
    const float* Wwn = (const float*)d_in[18], *bwn = (const float*)d_in[19];

    // ws layout: em (64) | tab_s (15.36) | tab_d (15.36) | [wn_t 7.68] | ints
    const size_t em_w  = (size_t)E_N * 32;             // u32 words
    const size_t tab_w = (size_t)V_N * 32;             // uint4 elems
    const size_t wn_w  = (size_t)V_N * 32;             // uint2 elems
    const size_t int_b = ((size_t)V_N * 3 + 1 + (size_t)E_N * 2) * 4;
    const size_t need_wn = em_w * 4 + tab_w * 16 * 2 + wn_w * 8 + int_b;
    const bool   wn_ok = (ws_size >= need_wn);

    unsigned* em     = (unsigned*)d_ws;
    uint4*    tab_s  = (uint4*)(em + em_w);
    uint4*    tab_d  = tab_s + tab_w;
    uint2*    wn_t   = (uint2*)(tab_d + tab_w);
    int*      ints   = wn_ok ? (int*)(wn_t + wn_w) : (int*)(tab_d + tab_w);
    int*      deg    = ints;                           // V (16B-aligned)
    int*      rowptr = deg + V_N;                      // V+1
    int*      cursor = rowptr + V_N + 1;               // V
    int2*     csr2   = (int2*)(cursor + V_N);          // E int2
    int*      perm   = (int*)(csr2 + E_N);             // V

    hipMemsetAsync(deg, 0, V_N * sizeof(int), stream);

    const int hbk = (E_N + 255) / 256;                 // 1954 blocks

    hist_k<<<hbk, 256, 0, stream>>>(dst, deg);
    scan_k<<<1, 1024, 0, stream>>>(deg, rowptr, cursor, perm);
    if (wn_ok) {
        fused_k1<true><<<K1B, 256, 0, stream>>>(
            nf, ef, src, dst, cursor, Was, bas, Wms, bms, Wad, bad, Wmd, bmd,
            Wae, bae, Wme, bme, Wwn, bwn, tab_s, tab_d, wn_t, csr2, em);
        node_gather6<true><<<3750, 256, 0, stream>>>(
            rowptr, csr2, em, tab_s, tab_d, wn_t, Wdot, Wwn, bwn, nf, perm,
            (float*)d_out);
    } else {
        fused_k1<false><<<K1B, 256, 0, stream>>>(
            nf, ef, src, dst, cursor, Was, bas, Wms, bms, Wad, bad, Wmd, bmd,
            Wae, bae, Wme, bme, Wwn, bwn, tab_s, tab_d, wn_t, csr2, em);
        node_gather6<false><<<3750, 256, 0, stream>>>(
            rowptr, csr2, em, tab_s, tab_d, wn_t, Wdot, Wwn, bwn, nf, perm,
            (float*)d_out);
    }
}

// Round 25
// 151.211 us; speedup vs baseline: 1.1529x; 1.0106x over previous
//
#include <hip/hip_runtime.h>
#include <hip/hip_bf16.h>

#define V_N 30000
#define E_N 500000
#define GWW 1536                               // gemv workers
#define SWW 1536                               // scatter workers (grid-stride)
#define XWW 1536                               // xform workers
#define K1B 4608                               // 512 periods of 9 (3:3:3)

typedef __attribute__((ext_vector_type(8))) short bf16x8;
typedef __attribute__((ext_vector_type(4))) float f32x4;

__device__ __forceinline__ float lrelu(float x) { return fmaxf(x, 0.2f * x); }
__device__ __forceinline__ unsigned short f2bf(float f) {
    __hip_bfloat16 h = __float2bfloat16(f);
    return *reinterpret_cast<unsigned short*>(&h);
}
__device__ __forceinline__ float bf_lo(unsigned u) { return __uint_as_float(u << 16); }
__device__ __forceinline__ float bf_hi(unsigned u) { return __uint_as_float(u & 0xffff0000u); }

// t + dpp(t); rows excluded by RMASK receive +0 (old=0, bound_ctrl).
template<int CTRL, int RMASK>
__device__ __forceinline__ float dpp_add(float t) {
    int b = __builtin_amdgcn_update_dpp(0, __float_as_int(t), CTRL, RMASK, 0xF, true);
    return t + __int_as_float(b);
}

// Sum over each independent 32-lane group, valid on all 32 lanes. (R13-proven)
__device__ __forceinline__ float group_sum(float t, int lane) {
    t = dpp_add<0x121, 0xF>(t);   // row_ror:1
    t = dpp_add<0x122, 0xF>(t);   // row_ror:2
    t = dpp_add<0x124, 0xF>(t);   // row_ror:4
    t = dpp_add<0x128, 0xF>(t);   // row_ror:8  -> each lane = its 16-row sum
    t = dpp_add<0x142, 0xA>(t);   // row_bcast15 -> rows 1,3 hold full 32-sum
    float u = __shfl_xor(t, 16);
    return (lane & 16) ? t : u;
}

// ---------------------------------------------------------------------------
// Histogram FIRST (standalone): unblocks scan immediately. (R23)
// ---------------------------------------------------------------------------
__global__ __launch_bounds__(256) void hist_k(
    const int* __restrict__ dst, int* __restrict__ deg)
{
    int i = blockIdx.x * 256 + threadIdx.x;
    if (i < E_N) atomicAdd(&deg[dst[i]], 1);
}

// ---------------------------------------------------------------------------
// Exclusive scan + counting sort, int4-vectorized (4 elems/thread):
// 8 chunk-iterations instead of 30 -> barrier latency cut ~3.75x.
// V_N = 7500*4 exactly; deg is 16B-aligned in the ws layout.
// ---------------------------------------------------------------------------
__global__ __launch_bounds__(1024) void scan_k(
    const int* __restrict__ deg, int* __restrict__ rowptr, int* __restrict__ cursor,
    int* __restrict__ perm)
{
    __shared__ int wsum[16];
    __shared__ int carry_s;
    __shared__ int bh[128];
    __shared__ int bc[128];
    int tid = threadIdx.x;
    int lane = tid & 63, wv = tid >> 6;
    if (tid == 0) carry_s = 0;
    if (tid < 128) bh[tid] = 0;
    __syncthreads();
    const int NG = V_N / 4;                    // 7500 int4 groups (exact)
    for (int base = 0; base < NG; base += 1024) {
        int gi = base + tid;
        int4 v = make_int4(0, 0, 0, 0);
        if (gi < NG) v = ((const int4*)deg)[gi];
        int s = v.x + v.y + v.z + v.w;
        int x = s;
        #pragma unroll
        for (int off = 1; off < 64; off <<= 1) {
            int t = __shfl_up(x, off, 64);
            if (lane >= off) x += t;
        }
        if (lane == 63) wsum[wv] = x;
        __syncthreads();
        if (wv == 0 && lane < 16) {
            int s2 = wsum[lane];
            #pragma unroll
            for (int off = 1; off < 16; off <<= 1) {
                int t = __shfl_up(s2, off, 64);
                if (lane >= off) s2 += t;
            }
            wsum[lane] = s2;
        }
        __syncthreads();
        int woff  = (wv == 0) ? 0 : wsum[wv - 1];
        int carry = carry_s;
        int excl  = carry + woff + x - s;
        if (gi < NG) {
            int i = gi * 4;
            int e0 = excl, e1 = e0 + v.x, e2 = e1 + v.y, e3 = e2 + v.z;
            rowptr[i] = e0; rowptr[i+1] = e1; rowptr[i+2] = e2; rowptr[i+3] = e3;
            cursor[i] = e0; cursor[i+1] = e1; cursor[i+2] = e2; cursor[i+3] = e3;
            atomicAdd(&bh[min(v.x, 127)], 1);
            atomicAdd(&bh[min(v.y, 127)], 1);
            atomicAdd(&bh[min(v.z, 127)], 1);
            atomicAdd(&bh[min(v.w, 127)], 1);
        }
        __syncthreads();
        if (tid == 1023) carry_s = carry + wsum[15];
        __syncthreads();
    }
    if (tid == 0) {
        rowptr[V_N] = carry_s;
        int off = 0;                           // descending: big bins first
        for (int b = 127; b >= 0; --b) { bc[b] = off; off += bh[b]; }
    }
    __syncthreads();
    for (int base = 0; base < NG; base += 1024) {
        int gi = base + tid;
        if (gi < NG) {
            int4 v = ((const int4*)deg)[gi];
            int i = gi * 4;
            int p0 = atomicAdd(&bc[min(v.x, 127)], 1); perm[p0] = i;
            int p1 = atomicAdd(&bc[min(v.y, 127)], 1); perm[p1] = i + 1;
            int p2 = atomicAdd(&bc[min(v.z, 127)], 1); perm[p2] = i + 2;
            int p3 = atomicAdd(&bc[min(v.w, 127)], 1); perm[p3] = i + 3;
        }
    }
}

// ---------------------------------------------------------------------------
// K1 (triple-fused, interleaved 3:3:3 — R24 rebalance: xform share 1/9 -> 3/9
// to kill the solo-tail that dominated R22/R23's K1 duration).
// w%9: [0,3)=gemv, [3,6)=CSR scatter (grid-stride), [6,9)=xform.
// ---------------------------------------------------------------------------
template<bool WN>
__global__ __launch_bounds__(256) void fused_k1(
    const float* __restrict__ nf, const float* __restrict__ ef,
    const int* __restrict__ src, const int* __restrict__ dst,
    int* __restrict__ cursor,
    const float* __restrict__ Was, const float* __restrict__ bas,
    const float* __restrict__ Wms, const float* __restrict__ bms,
    const float* __restrict__ Wad, const float* __restrict__ bad,
    const float* __restrict__ Wmd, const float* __restrict__ bmd,
    const float* __restrict__ Wae, const float* __restrict__ bae,
    const float* __restrict__ Wme, const float* __restrict__ bme,
    const float* __restrict__ Wwn, const float* __restrict__ bwn,
    uint4* __restrict__ tab_s, uint4* __restrict__ tab_d,
    uint2* __restrict__ wn_t,
    int2* __restrict__ csr2, unsigned* __restrict__ em)
{
    int tid  = threadIdx.x;
    int w    = blockIdx.x;
    int p    = w % 9, slot = w / 9;
    if (p < 3) {                               // ---- edge GEMV (1536 wkr) ----
        int gw = slot * 3 + p;
        int lane = tid & 63;
        int l15 = lane & 15, q = lane >> 4;
        bf16x8 B0, B1, B2, B3;
        #pragma unroll
        for (int i = 0; i < 8; ++i) {
            int k = q * 8 + i;
            B0[i] = (short)f2bf(Wae[k * 32 + l15]);
            B1[i] = (short)f2bf(Wae[k * 32 + 16 + l15]);
            B2[i] = (short)f2bf(Wme[k * 32 + l15]);
            B3[i] = (short)f2bf(Wme[k * 32 + 16 + l15]);
        }
        float ba0 = bae[l15], ba1 = bae[16 + l15];
        float bm0 = bme[l15], bm1 = bme[16 + l15];
        int wid = (gw * 256 + tid) >> 6;
        int nw  = (GWW * 256) >> 6;            // 6144 waves
        const int ntiles = E_N / 16;           // 31250 exact
        for (int tile = wid; tile < ntiles; tile += nw) {
            int ebase = tile * 16;
            const float4* ap = (const float4*)(ef + (size_t)(ebase + l15) * 32 + q * 8);
            float4 a0 = ap[0], a1 = ap[1];
            bf16x8 A;
            A[0] = (short)f2bf(a0.x); A[1] = (short)f2bf(a0.y);
            A[2] = (short)f2bf(a0.z); A[3] = (short)f2bf(a0.w);
            A[4] = (short)f2bf(a1.x); A[5] = (short)f2bf(a1.y);
            A[6] = (short)f2bf(a1.z); A[7] = (short)f2bf(a1.w);
            f32x4 z = {0.f, 0.f, 0.f, 0.f};
            f32x4 D0 = __builtin_amdgcn_mfma_f32_16x16x32_bf16(A, B0, z, 0, 0, 0);
            f32x4 D1 = __builtin_amdgcn_mfma_f32_16x16x32_bf16(A, B1, z, 0, 0, 0);
            f32x4 D2 = __builtin_amdgcn_mfma_f32_16x16x32_bf16(A, B2, z, 0, 0, 0);
            f32x4 D3 = __builtin_amdgcn_mfma_f32_16x16x32_bf16(A, B3, z, 0, 0, 0);
            #pragma unroll
            for (int j = 0; j < 4; ++j) {
                int e = ebase + q * 4 + j;     // edge-order write, coalesced
                unsigned lo = f2bf(D0[j] + ba0) | ((unsigned)f2bf(D2[j] + bm0) << 16);
                unsigned hi = f2bf(D1[j] + ba1) | ((unsigned)f2bf(D3[j] + bm1) << 16);
                em[(size_t)e * 32 + l15]      = lo;
                em[(size_t)e * 32 + 16 + l15] = hi;
            }
        }
        return;
    }
    if (p < 6) {                               // ---- CSR scatter (1536 wkr) ----
        int sw = slot * 3 + (p - 3);
        for (int i = sw * 256 + tid; i < E_N; i += SWW * 256) {
            int pp = atomicAdd(&cursor[dst[i]], 1);
            csr2[pp] = make_int2(src[i], i);
        }
        return;
    }
    // ---- node transform (1536 wkr): 4 matrices + optional Wwn (R21-proven) ----
    int bid = slot * 3 + (p - 6);
    int lane = tid & 63;
    int l15 = lane & 15, q = lane >> 4;
    bf16x8 Bas0, Bas1, Bad0, Bad1, Bms0, Bms1, Bmd0, Bmd1, Bwn0, Bwn1;
    #pragma unroll
    for (int i = 0; i < 8; ++i) {
        int k = q * 8 + i;
        Bas0[i] = (short)f2bf(Was[k * 32 + l15]);
        Bas1[i] = (short)f2bf(Was[k * 32 + 16 + l15]);
        Bad0[i] = (short)f2bf(Wad[k * 32 + l15]);
        Bad1[i] = (short)f2bf(Wad[k * 32 + 16 + l15]);
        Bms0[i] = (short)f2bf(Wms[k * 32 + l15]);
        Bms1[i] = (short)f2bf(Wms[k * 32 + 16 + l15]);
        Bmd0[i] = (short)f2bf(Wmd[k * 32 + l15]);
        Bmd1[i] = (short)f2bf(Wmd[k * 32 + 16 + l15]);
        if (WN) {
            Bwn0[i] = (short)f2bf(Wwn[k * 32 + l15]);
            Bwn1[i] = (short)f2bf(Wwn[k * 32 + 16 + l15]);
        }
    }
    float bs0 = bas[l15], bs1 = bas[16 + l15];
    float bd0 = bad[l15], bd1 = bad[16 + l15];
    float bm0 = bms[l15], bm1 = bms[16 + l15];
    float bn0 = bmd[l15], bn1 = bmd[16 + l15];
    float bw0 = WN ? bwn[l15] : 0.f, bw1 = WN ? bwn[16 + l15] : 0.f;

    int wv = tid >> 6;                         // wave in block (0..3)
    const int ntiles = V_N / 4;                // 7500 (4 nodes per tile)
    for (int tile = bid * 4 + wv; tile < ntiles; tile += XWW * 4) {
        int nbase = tile * 4;
        int rbase = nbase * 4;                 // 16 node-head rows
        const float4* ap = (const float4*)(nf + (size_t)(rbase + l15) * 32 + q * 8);
        float4 a0 = ap[0], a1 = ap[1];
        bf16x8 A;
        A[0] = (short)f2bf(a0.x); A[1] = (short)f2bf(a0.y);
        A[2] = (short)f2bf(a0.z); A[3] = (short)f2bf(a0.w);
        A[4] = (short)f2bf(a1.x); A[5] = (short)f2bf(a1.y);
        A[6] = (short)f2bf(a1.z); A[7] = (short)f2bf(a1.w);
        f32x4 z = {0.f, 0.f, 0.f, 0.f};
        f32x4 Das0 = __builtin_amdgcn_mfma_f32_16x16x32_bf16(A, Bas0, z, 0, 0, 0);
        f32x4 Das1 = __builtin_amdgcn_mfma_f32_16x16x32_bf16(A, Bas1, z, 0, 0, 0);
        f32x4 Dad0 = __builtin_amdgcn_mfma_f32_16x16x32_bf16(A, Bad0, z, 0, 0, 0);
        f32x4 Dad1 = __builtin_amdgcn_mfma_f32_16x16x32_bf16(A, Bad1, z, 0, 0, 0);
        f32x4 Dms0 = __builtin_amdgcn_mfma_f32_16x16x32_bf16(A, Bms0, z, 0, 0, 0);
        f32x4 Dms1 = __builtin_amdgcn_mfma_f32_16x16x32_bf16(A, Bms1, z, 0, 0, 0);
        f32x4 Dmd0 = __builtin_amdgcn_mfma_f32_16x16x32_bf16(A, Bmd0, z, 0, 0, 0);
        f32x4 Dmd1 = __builtin_amdgcn_mfma_f32_16x16x32_bf16(A, Bmd1, z, 0, 0, 0);
        int node = nbase + q;
        uint4 lo, hi;
        lo.x = f2bf(Das0[0] + bs0) | ((unsigned)f2bf(Das0[1] + bs0) << 16);
        lo.y = f2bf(Das0[2] + bs0) | ((unsigned)f2bf(Das0[3] + bs0) << 16);
        lo.z = f2bf(Dms0[0] + bm0) | ((unsigned)f2bf(Dms0[1] + bm0) << 16);
        lo.w = f2bf(Dms0[2] + bm0) | ((unsigned)f2bf(Dms0[3] + bm0) << 16);
        hi.x = f2bf(Das1[0] + bs1) | ((unsigned)f2bf(Das1[1] + bs1) << 16);
        hi.y = f2bf(Das1[2] + bs1) | ((unsigned)f2bf(Das1[3] + bs1) << 16);
        hi.z = f2bf(Dms1[0] + bm1) | ((unsigned)f2bf(Dms1[1] + bm1) << 16);
        hi.w = f2bf(Dms1[2] + bm1) | ((unsigned)f2bf(Dms1[3] + bm1) << 16);
        tab_s[(size_t)node * 32 + l15]      = lo;
        tab_s[(size_t)node * 32 + 16 + l15] = hi;
        uint4 lod, hid;
        lod.x = f2bf(Dad0[0] + bd0) | ((unsigned)f2bf(Dad0[1] + bd0) << 16);
        lod.y = f2bf(Dad0[2] + bd0) | ((unsigned)f2bf(Dad0[3] + bd0) << 16);
        lod.z = f2bf(Dmd0[0] + bn0) | ((unsigned)f2bf(Dmd0[1] + bn0) << 16);
        lod.w = f2bf(Dmd0[2] + bn0) | ((unsigned)f2bf(Dmd0[3] + bn0) << 16);
        hid.x = f2bf(Dad1[0] + bd1) | ((unsigned)f2bf(Dad1[1] + bd1) << 16);
        hid.y = f2bf(Dad1[2] + bd1) | ((unsigned)f2bf(Dad1[3] + bd1) << 16);
        hid.z = f2bf(Dmd1[0] + bn1) | ((unsigned)f2bf(Dmd1[1] + bn1) << 16);
        hid.w = f2bf(Dmd1[2] + bn1) | ((unsigned)f2bf(Dmd1[3] + bn1) << 16);
        tab_d[(size_t)node * 32 + l15]      = lod;
        tab_d[(size_t)node * 32 + 16 + l15] = hid;
        if (WN) {
            f32x4 Dwn0 = __builtin_amdgcn_mfma_f32_16x16x32_bf16(A, Bwn0, z, 0, 0, 0);
            f32x4 Dwn1 = __builtin_amdgcn_mfma_f32_16x16x32_bf16(A, Bwn1, z, 0, 0, 0);
            uint2 w0, w1;
            w0.x = f2bf(Dwn0[0] + bw0) | ((unsigned)f2bf(Dwn0[1] + bw0) << 16);
            w0.y = f2bf(Dwn0[2] + bw0) | ((unsigned)f2bf(Dwn0[3] + bw0) << 16);
            w1.x = f2bf(Dwn1[0] + bw1) | ((unsigned)f2bf(Dwn1[1] + bw1) << 16);
            w1.y = f2bf(Dwn1[2] + bw1) | ((unsigned)f2bf(Dwn1[3] + bw1) << 16);
            wn_t[(size_t)node * 32 + l15]      = w0;
            wn_t[(size_t)node * 32 + 16 + l15] = w1;
        }
    }
}

// ---------------------------------------------------------------------------
// Kernel C: per-dst aggregation, degree-sorted via perm[]. (R21/R22-proven)
// WN: epilogue = 1 uint2 bf16 table load; !WN: in-kernel Wwn GEMV fallback.
// ---------------------------------------------------------------------------
template<bool WN>
__global__ __launch_bounds__(256) void node_gather6(
    const int* __restrict__ rowptr, const int2* __restrict__ csr2,
    const unsigned* __restrict__ em, const uint4* __restrict__ tab_s,
    const uint4* __restrict__ tab_d, const uint2* __restrict__ wn_t,
    const float* __restrict__ Wdot,
    const float* __restrict__ Wwn, const float* __restrict__ bwn,
    const float* __restrict__ nf,
    const int* __restrict__ perm,
    float* __restrict__ out)
{
    __shared__ float ww[WN ? 1 : 1024];
    __shared__ float wd[32];
    int tid = threadIdx.x;
    if (!WN) for (int i = tid; i < 1024; i += 256) ww[i] = Wwn[i];
    if (tid < 32) wd[tid] = Wdot[tid] * 1.4426950408889634f;   // log2(e)
    __syncthreads();
    int lane = tid & 31;
    int n = perm[blockIdx.x * 8 + (tid >> 5)]; // degree-sorted assignment
    float wdl = wd[lane];

    float da[4], dm[4];
    {
        uint4 v = tab_d[(size_t)n * 32 + lane];
        da[0] = bf_lo(v.x); da[1] = bf_hi(v.x);
        da[2] = bf_lo(v.y); da[3] = bf_hi(v.y);
        dm[0] = bf_lo(v.z); dm[1] = bf_hi(v.z);
        dm[2] = bf_lo(v.w); dm[3] = bf_hi(v.w);
    }

    float acc0 = 0.f, acc1 = 0.f, acc2 = 0.f, acc3 = 0.f;
    float s0 = 0.f, s1 = 0.f, s2 = 0.f, s3 = 0.f;
    int p0 = rowptr[n], p1 = rowptr[n + 1];

    uint4 gc = make_uint4(0, 0, 0, 0);
    unsigned ec = 0;
    if (p0 < p1) {
        int2 c = csr2[p0];
        gc = tab_s[(size_t)c.x * 32 + lane];
        ec = em[(size_t)c.y * 32 + lane];
    }
    for (int p = p0; p < p1; ++p) {
        uint4 g = gc; unsigned ev = ec;
        if (p + 1 < p1) {                      // depth-1 prefetch
            int2 c = csr2[p + 1];
            gc = tab_s[(size_t)c.x * 32 + lane];
            ec = em[(size_t)c.y * 32 + lane];
        }
        float ea = bf_lo(ev), me = bf_hi(ev);
        float t0 = lrelu(bf_lo(g.x) + da[0] + ea) * wdl;
        float t1 = lrelu(bf_hi(g.x) + da[1] + ea) * wdl;
        float t2 = lrelu(bf_lo(g.y) + da[2] + ea) * wdl;
        float t3 = lrelu(bf_hi(g.y) + da[3] + ea) * wdl;
        t0 = group_sum(t0, lane);
        t1 = group_sum(t1, lane);
        t2 = group_sum(t2, lane);
        t3 = group_sum(t3, lane);
        float x0 = exp2f(t0), x1 = exp2f(t1);
        float x2 = exp2f(t2), x3 = exp2f(t3);
        float m0 = lrelu(bf_lo(g.z) + dm[0] + me);
        float m1 = lrelu(bf_hi(g.z) + dm[1] + me);
        float m2 = lrelu(bf_lo(g.w) + dm[2] + me);
        float m3 = lrelu(bf_hi(g.w) + dm[3] + me);
        acc0 = fmaf(x0, m0, acc0); s0 += x0;
        acc1 = fmaf(x1, m1, acc1); s1 += x1;
        acc2 = fmaf(x2, m2, acc2); s2 += x2;
        acc3 = fmaf(x3, m3, acc3); s3 += x3;
    }
    if (WN) {
        uint2 w = wn_t[(size_t)n * 32 + lane];
        float wn0 = bf_lo(w.x), wn1 = bf_hi(w.x);
        float wn2 = bf_lo(w.y), wn3 = bf_hi(w.y);
        float f0 = (s0 > 0.f) ? acc0 / s0 : 0.f;
        float f1 = (s1 > 0.f) ? acc1 / s1 : 0.f;
        float f2 = (s2 > 0.f) ? acc2 / s2 : 0.f;
        float f3 = (s3 > 0.f) ? acc3 / s3 : 0.f;
        size_t ob = (size_t)n * 128 + lane;
        out[ob]      = lrelu(f0 + wn0);
        out[ob + 32] = lrelu(f1 + wn1);
        out[ob + 64] = lrelu(f2 + wn2);
        out[ob + 96] = lrelu(f3 + wn3);
    } else {
        #pragma unroll
        for (int h = 0; h < 4; ++h) {
            float x = nf[(size_t)n * 128 + h * 32 + lane];
            float a = bwn[lane];
            #pragma unroll
            for (int k = 0; k < 32; ++k)
                a = fmaf(__shfl(x, k, 32), ww[k * 32 + lane], a);
            float accv = (h == 0) ? acc0 : (h == 1) ? acc1 : (h == 2) ? acc2 : acc3;
            float sv   = (h == 0) ? s0   : (h == 1) ? s1   : (h == 2) ? s2   : s3;
            float f = (sv > 0.f) ? accv / sv : 0.f;
            out[(size_t)n * 128 + h * 32 + lane] = lrelu(f + a);
        }
    }
}

extern "C" void kernel_launch(void* const* d_in, const int* in_sizes, int n_in,
                              void* d_out, int out_size, void* d_ws, size_t ws_size,
                              hipStream_t stream)
{
    const float* nf  = (const float*)d_in[0];
    const float* ef  = (const float*)d_in[1];
    const int*   src = (const int*)d_in[2];
    const int*   dst = (const int*)d_in[3];
    const float* Was = (const float*)d_in[4],  *bas = (const float*)d_in[5];
    const float* Wad = (const float*)d_in[6],  *bad = (const float*)d_in[7];
    const float* Wae = (const float*)d_in[8],  *bae = (const float*)d_in[9];
    const float* Wdot= (const float*)d_in[10];
    const float* Wms = (const float*)d_in[12], *bms = (const float*)d_in[13];
    const float* Wmd = (const float*)d_in[14], *bmd = (const float*)d_in[15];
    const float* Wme = (const float*)d_in[16], *bme = (const float*)d_in[17];
    const float* Wwn = (const float*)d_in[18], *bwn = (const float*)d_in[19];

    // ws layout: em (64) | tab_s (15.36) | tab_d (15.36) | [wn_t 7.68] | ints
    const size_t em_w  = (size_t)E_N * 32;             // u32 words
    const size_t tab_w = (size_t)V_N * 32;             // uint4 elems
    const size_t wn_w  = (size_t)V_N * 32;             // uint2 elems
    const size_t int_b = ((size_t)V_N * 3 + 1 + (size_t)E_N * 2) * 4;
    const size_t need_wn = em_w * 4 + tab_w * 16 * 2 + wn_w * 8 + int_b;
    const bool   wn_ok = (ws_size >= need_wn);

    unsigned* em     = (unsigned*)d_ws;
    uint4*    tab_s  = (uint4*)(em + em_w);
    uint4*    tab_d  = tab_s + tab_w;
    uint2*    wn_t   = (uint2*)(tab_d + tab_w);
    int*      ints   = wn_ok ? (int*)(wn_t + wn_w) : (int*)(tab_d + tab_w);
    int*      deg    = ints;                           // V (16B-aligned)
    int*      rowptr = deg + V_N;                      // V+1
    int*      cursor = rowptr + V_N + 1;               // V
    int2*     csr2   = (int2*)(cursor + V_N);          // E int2
    int*      perm   = (int*)(csr2 + E_N);             // V

    hipMemsetAsync(deg, 0, V_N * sizeof(int), stream);

    const int hbk = (E_N + 255) / 256;                 // 1954 blocks

    hist_k<<<hbk, 256, 0, stream>>>(dst, deg);
    scan_k<<<1, 1024, 0, stream>>>(deg, rowptr, cursor, perm);
    if (wn_ok) {
        fused_k1<true><<<K1B, 256, 0, stream>>>(
            nf, ef, src, dst, cursor, Was, bas, Wms, bms, Wad, bad, Wmd, bmd,
            Wae, bae, Wme, bme, Wwn, bwn, tab_s, tab_d, wn_t, csr2, em);
        node_gather6<true><<<3750, 256, 0, stream>>>(
            rowptr, csr2, em, tab_s, tab_d, wn_t, Wdot, Wwn, bwn, nf, perm,
            (float*)d_out);
    } else {
        fused_k1<false><<<K1B, 256, 0, stream>>>(
            nf, ef, src, dst, cursor, Was, bas, Wms, bms, Wad, bad, Wmd, bmd,
            Wae, bae, Wme, bme, Wwn, bwn, tab_s, tab_d, wn_t, csr2, em);
        node_gather6<false><<<3750, 256, 0, stream>>>(
            rowptr, csr2, em, tab_s, tab_d, wn_t, Wdot, Wwn, bwn, nf, perm,
            (float*)d_out);
    }
}